// Round 5
// baseline (233.815 us; speedup 1.0000x reference)
//
#include <hip/hip_runtime.h>
#include <math.h>

#define NPOS 4096
#define DCH  512
#define HD   32
#define NH   16
#define KW   9
#define DIL  3
#define PAD  12
#define TILE   128
#define NTILES (NPOS / TILE)       // 32
#define SPANT  (TILE + 2*PAD)      // 152 tokens staged per tile
#define ROWF4  (SPANT / 4)         // 38 float4 per channel row
#define SLDS   156                 // LDS row stride in bf16 elems (312 B = 39*8)
#define CSPL   8                   // channel-split lanes per token-group
#define CPT    (HD / CSPL)         // 4 channels per thread
#define TPT    4                   // tokens per thread
#define WSPAN  28                  // 4 tokens x 9 taps span 28 tokens

typedef unsigned short ushort_t;

__device__ __forceinline__ ushort_t f2bf(float f) {
    unsigned u = __float_as_uint(f);
    unsigned r = (u + 0x7FFFu + ((u >> 16) & 1u)) >> 16;   // RNE
    return (ushort_t)r;
}
__device__ __forceinline__ float bf2f(ushort_t h) {
    return __uint_as_float(((unsigned)h) << 16);
}

__global__ __launch_bounds__(256, 5) void dilate_attn_kernel(
    const float* __restrict__ q,
    const float* __restrict__ k,
    const float* __restrict__ v,
    float* __restrict__ out)
{
    __shared__ ushort_t ks[HD * SLDS];   // bf16 k tile: 9984 B
    __shared__ ushort_t vs[HD * SLDS];   // bf16 v tile: 9984 B

    const int bh   = blockIdx.x >> 5;            // 0..63  (b*16+h)
    const int tile = blockIdx.x & (NTILES - 1);  // 0..31
    const int n0t  = tile * TILE;                // first token of tile
    const int ws   = n0t - PAD;                  // staged span start (may be <0)

    const size_t cb = (size_t)bh * HD * NPOS;
    const float* kg = k + cb;
    const float* vg = v + cb;
    const float* qg = q + cb;

    // ---------------- Stage k,v spans into LDS as bf16 (coalesced float4) --
    const bool easy = (ws >= 0) && (ws + SPANT <= NPOS);
    for (int p = threadIdx.x; p < HD * ROWF4; p += 256) {
        int row = p / ROWF4;                     // channel 0..31
        int c4  = p - row * ROWF4;               // float4 col 0..37
        int g0  = ws + c4 * 4;
        const float* kr = kg + (size_t)row * NPOS;
        const float* vr = vg + (size_t)row * NPOS;
        float4 kk, vv;
        if (easy || (g0 >= 0 && g0 + 4 <= NPOS)) {
            kk = *(const float4*)(kr + g0);
            vv = *(const float4*)(vr + g0);
        } else {                                  // edge tiles: clamped scalar
            int i0 = min(max(g0 + 0, 0), NPOS - 1);
            int i1 = min(max(g0 + 1, 0), NPOS - 1);
            int i2 = min(max(g0 + 2, 0), NPOS - 1);
            int i3 = min(max(g0 + 3, 0), NPOS - 1);
            kk = make_float4(kr[i0], kr[i1], kr[i2], kr[i3]);
            vv = make_float4(vr[i0], vr[i1], vr[i2], vr[i3]);
        }
        ushort4 kb; kb.x = f2bf(kk.x); kb.y = f2bf(kk.y); kb.z = f2bf(kk.z); kb.w = f2bf(kk.w);
        ushort4 vb; vb.x = f2bf(vv.x); vb.y = f2bf(vv.y); vb.z = f2bf(vv.z); vb.w = f2bf(vv.w);
        *(ushort4*)&ks[row * SLDS + c4 * 4] = kb;   // byte ofs = row*312 + c4*8, 8B-aligned
        *(ushort4*)&vs[row * SLDS + c4 * 4] = vb;
    }

    // ---------------- q loads (global, coalesced fp32; overlap staging) ----
    const int cs = threadIdx.x & (CSPL - 1);     // lane&7: channel quad slot
    const int lg = threadIdx.x >> 3;             // 0..31: token group in tile
    const int n0 = n0t + lg * TPT;               // first token this thread owns

    float4 qv[CPT];
#pragma unroll
    for (int i = 0; i < CPT; ++i) {
        int ch = cs * CPT + i;
        qv[i] = *(const float4*)(qg + (size_t)ch * NPOS + n0);
    }

    __syncthreads();

    // ---------------- Pass 1: partial scores from LDS k --------------------
    float s[TPT][KW];
#pragma unroll
    for (int t = 0; t < TPT; ++t)
#pragma unroll
        for (int j = 0; j < KW; ++j) s[t][j] = 0.0f;

#pragma unroll
    for (int i = 0; i < CPT; ++i) {
        int row = cs * CPT + i;
        const ushort4* wp = (const ushort4*)&ks[row * SLDS + lg * TPT];
        float w[WSPAN];
#pragma unroll
        for (int u = 0; u < WSPAN / 4; ++u) {
            ushort4 x = wp[u];
            w[4*u]   = bf2f(x.x); w[4*u+1] = bf2f(x.y);
            w[4*u+2] = bf2f(x.z); w[4*u+3] = bf2f(x.w);
        }
        float qt[TPT] = {qv[i].x, qv[i].y, qv[i].z, qv[i].w};
#pragma unroll
        for (int t = 0; t < TPT; ++t)
#pragma unroll
            for (int j = 0; j < KW; ++j)
                s[t][j] = fmaf(qt[t], w[t + 3*j], s[t][j]);
    }

    // Reduce partial scores across the 8 channel-split lanes
#pragma unroll
    for (int t = 0; t < TPT; ++t)
#pragma unroll
        for (int j = 0; j < KW; ++j) {
            float x = s[t][j];
            x += __shfl_xor(x, 1);
            x += __shfl_xor(x, 2);
            x += __shfl_xor(x, 4);
            s[t][j] = x;
        }

    // ---------------- Softmax per token (invalid taps: logit exactly 0) ----
    const float scale = 0.17677669529663687f;    // 32^-0.5
#pragma unroll
    for (int t = 0; t < TPT; ++t) {
        float m = -INFINITY;
#pragma unroll
        for (int j = 0; j < KW; ++j) {
            float valid = ((unsigned)(n0 + t + 3*j - PAD) < NPOS) ? 1.0f : 0.0f;
            float x = s[t][j] * scale * valid;
            s[t][j] = x;
            m = fmaxf(m, x);
        }
        float sum = 0.0f;
#pragma unroll
        for (int j = 0; j < KW; ++j) {
            float e = __expf(s[t][j] - m);
            s[t][j] = e;
            sum += e;
        }
        float inv = 1.0f / sum;
#pragma unroll
        for (int j = 0; j < KW; ++j) {
            float valid = ((unsigned)(n0 + t + 3*j - PAD) < NPOS) ? 1.0f : 0.0f;
            s[t][j] *= inv * valid;              // s now holds probabilities
        }
    }

    // ---------------- Pass 2: output from LDS v ----------------------------
    float o[TPT][CPT];
#pragma unroll
    for (int t = 0; t < TPT; ++t)
#pragma unroll
        for (int i = 0; i < CPT; ++i) o[t][i] = 0.0f;

#pragma unroll
    for (int i = 0; i < CPT; ++i) {
        int row = cs * CPT + i;
        const ushort4* wp = (const ushort4*)&vs[row * SLDS + lg * TPT];
        float w[WSPAN];
#pragma unroll
        for (int u = 0; u < WSPAN / 4; ++u) {
            ushort4 x = wp[u];
            w[4*u]   = bf2f(x.x); w[4*u+1] = bf2f(x.y);
            w[4*u+2] = bf2f(x.z); w[4*u+3] = bf2f(x.w);
        }
#pragma unroll
        for (int t = 0; t < TPT; ++t)
#pragma unroll
            for (int j = 0; j < KW; ++j)
                o[t][i] = fmaf(s[t][j], w[t + 3*j], o[t][i]);
    }

    // ---------------- Store: one float4 per token --------------------------
    const int b  = bh >> 4;
    const int hh = bh & (NH - 1);
#pragma unroll
    for (int t = 0; t < TPT; ++t) {
        float* op = out + ((size_t)(b * NPOS + n0 + t)) * DCH + hh * HD + cs * CPT;
        *(float4*)op = make_float4(o[t][0], o[t][1], o[t][2], o[t][3]);
    }
}

extern "C" void kernel_launch(void* const* d_in, const int* in_sizes, int n_in,
                              void* d_out, int out_size, void* d_ws, size_t ws_size,
                              hipStream_t stream) {
    const float* q = (const float*)d_in[0];
    const float* k = (const float*)d_in[1];
    const float* v = (const float*)d_in[2];
    float* out = (float*)d_out;

    const int grid = 4 * NH * NTILES;   // 64 bh * 32 tiles = 2048 blocks
    hipLaunchKernelGGL(dilate_attn_kernel, dim3(grid), dim3(256), 0, stream,
                       q, k, v, out);
}

// Round 6
// 154.486 us; speedup vs baseline: 1.5135x; 1.5135x over previous
//
#include <hip/hip_runtime.h>
#include <math.h>

#define NPOS 4096
#define DCH  512
#define HD   32
#define NH   16
#define KW   9
#define DIL  3
#define PAD  12
#define TILE   128
#define NTILES (NPOS / TILE)       // 32
#define SPANT  (TILE + 2*PAD)      // 152 tokens staged per tile
#define ROWF4  (SPANT / 4)         // 38 float4 per channel row
#define SLDS   156                 // LDS row stride in floats (pad vs 152)
#define CSPL   8                   // channel-split lanes per token-group
#define CPT    (HD / CSPL)         // 4 channels per thread
#define TPT    4                   // tokens per thread
#define WSPAN  28                  // 4 tokens x 9 taps span 28 tokens
#define NT4    4                   // tiles per block (pipeline length)
#define NLD    5                   // staging float4 loads per thread (last partial)

__global__ __launch_bounds__(256) void dilate_attn_kernel(
    const float* __restrict__ q,
    const float* __restrict__ k,
    const float* __restrict__ v,
    float* __restrict__ out)
{
    __shared__ float ks[2][HD * SLDS];   // double-buffered k tile (fp32)
    __shared__ float vs[2][HD * SLDS];   // double-buffered v tile (fp32)

    const int tid   = threadIdx.x;
    const int tseq0 = blockIdx.x * NT4;          // first global tile index
    const int bh    = tseq0 >> 5;                // constant within block
    const int tile0 = tseq0 & (NTILES - 1);      // 4-aligned, never crosses row

    const size_t cb = (size_t)bh * HD * NPOS;
    const float* kg = k + cb;
    const float* vg = v + cb;
    const float* qg = q + cb;

    // Staging decomposition (iteration-invariant): p = tid + u*256 -> (row, col)
    int  srow[NLD], scol[NLD];
    bool sact[NLD];
#pragma unroll
    for (int u = 0; u < NLD; ++u) {
        int p = tid + u * 256;
        sact[u] = (p < HD * ROWF4);              // 1216 items over 256 threads
        int pp = sact[u] ? p : 0;
        srow[u] = pp / ROWF4;
        scol[u] = (pp - srow[u] * ROWF4) * 4;    // token offset within span
    }

    const int cs = tid & (CSPL - 1);             // channel quad slot
    const int lg = tid >> 3;                     // token group within tile

    // ---- prefetch: global -> registers for tile `tl` ----
    auto load_tile = [&](int tl, float4* kr, float4* vr, float4* qn) {
        const int ws = tl * TILE - PAD;
        const bool easy = (tl > 0) && (tl < NTILES - 1);
#pragma unroll
        for (int u = 0; u < NLD; ++u) {
            if (!sact[u]) continue;
            int g0 = ws + scol[u];
            const float* krow = kg + (size_t)srow[u] * NPOS;
            const float* vrow = vg + (size_t)srow[u] * NPOS;
            if (easy || (g0 >= 0 && g0 + 4 <= NPOS)) {
                kr[u] = *(const float4*)(krow + g0);
                vr[u] = *(const float4*)(vrow + g0);
            } else {                              // edge tiles only
                int i0 = min(max(g0 + 0, 0), NPOS - 1);
                int i1 = min(max(g0 + 1, 0), NPOS - 1);
                int i2 = min(max(g0 + 2, 0), NPOS - 1);
                int i3 = min(max(g0 + 3, 0), NPOS - 1);
                kr[u] = make_float4(krow[i0], krow[i1], krow[i2], krow[i3]);
                vr[u] = make_float4(vrow[i0], vrow[i1], vrow[i2], vrow[i3]);
            }
        }
        int n0 = tl * TILE + lg * TPT;
#pragma unroll
        for (int i = 0; i < CPT; ++i)
            qn[i] = *(const float4*)(qg + (size_t)(cs * CPT + i) * NPOS + n0);
    };

    auto write_lds = [&](int buf, const float4* kr, const float4* vr) {
#pragma unroll
        for (int u = 0; u < NLD; ++u) {
            if (!sact[u]) continue;
            *(float4*)&ks[buf][srow[u] * SLDS + scol[u]] = kr[u];
            *(float4*)&vs[buf][srow[u] * SLDS + scol[u]] = vr[u];
        }
    };

    // ---- prologue: stage first tile ----
    float4 qv[CPT];
    {
        float4 ka[NLD], va[NLD];
        load_tile(tile0, ka, va, qv);
        write_lds(0, ka, va);
    }
    __syncthreads();

    const float scale = 0.17677669529663687f;    // 32^-0.5
    const int b  = bh >> 4;
    const int hh = bh & (NH - 1);

#pragma unroll 1
    for (int it = 0; it < NT4; ++it) {
        const int cur = it & 1;
        const int tl  = tile0 + it;
        const int n0  = tl * TILE + lg * TPT;

        // Issue next tile's loads FIRST (latency hides behind compute below)
        float4 kn[NLD], vn[NLD], qn[CPT];
        if (it + 1 < NT4) load_tile(tl + 1, kn, vn, qn);

        // ---------------- Pass 1: partial scores from LDS k ----------------
        float s[TPT][KW];
#pragma unroll
        for (int t = 0; t < TPT; ++t)
#pragma unroll
            for (int j = 0; j < KW; ++j) s[t][j] = 0.0f;

#pragma unroll
        for (int i = 0; i < CPT; ++i) {
            int row = cs * CPT + i;
            const float4* wp = (const float4*)&ks[cur][row * SLDS + lg * TPT];
            float w[WSPAN];
#pragma unroll
            for (int u = 0; u < WSPAN / 4; ++u) {
                float4 x = wp[u];
                w[4*u] = x.x; w[4*u+1] = x.y; w[4*u+2] = x.z; w[4*u+3] = x.w;
            }
            float qt[TPT] = {qv[i].x, qv[i].y, qv[i].z, qv[i].w};
#pragma unroll
            for (int t = 0; t < TPT; ++t)
#pragma unroll
                for (int j = 0; j < KW; ++j)
                    s[t][j] = fmaf(qt[t], w[t + 3*j], s[t][j]);
        }

        // Reduce partials across the 8 channel-split lanes
#pragma unroll
        for (int t = 0; t < TPT; ++t)
#pragma unroll
            for (int j = 0; j < KW; ++j) {
                float x = s[t][j];
                x += __shfl_xor(x, 1);
                x += __shfl_xor(x, 2);
                x += __shfl_xor(x, 4);
                s[t][j] = x;
            }

        // ---------------- Softmax (invalid taps: logit exactly 0) ----------
#pragma unroll
        for (int t = 0; t < TPT; ++t) {
            float m = -INFINITY;
#pragma unroll
            for (int j = 0; j < KW; ++j) {
                float valid = ((unsigned)(n0 + t + 3*j - PAD) < NPOS) ? 1.0f : 0.0f;
                float x = s[t][j] * scale * valid;
                s[t][j] = x;
                m = fmaxf(m, x);
            }
            float sum = 0.0f;
#pragma unroll
            for (int j = 0; j < KW; ++j) {
                float e = __expf(s[t][j] - m);
                s[t][j] = e;
                sum += e;
            }
            float inv = 1.0f / sum;
#pragma unroll
            for (int j = 0; j < KW; ++j) {
                float valid = ((unsigned)(n0 + t + 3*j - PAD) < NPOS) ? 1.0f : 0.0f;
                s[t][j] *= inv * valid;          // s now holds probabilities
            }
        }

        // ---------------- Pass 2: output from LDS v ------------------------
        float o[TPT][CPT];
#pragma unroll
        for (int t = 0; t < TPT; ++t)
#pragma unroll
            for (int i = 0; i < CPT; ++i) o[t][i] = 0.0f;

#pragma unroll
        for (int i = 0; i < CPT; ++i) {
            int row = cs * CPT + i;
            const float4* wp = (const float4*)&vs[cur][row * SLDS + lg * TPT];
            float w[WSPAN];
#pragma unroll
            for (int u = 0; u < WSPAN / 4; ++u) {
                float4 x = wp[u];
                w[4*u] = x.x; w[4*u+1] = x.y; w[4*u+2] = x.z; w[4*u+3] = x.w;
            }
#pragma unroll
            for (int t = 0; t < TPT; ++t)
#pragma unroll
                for (int j = 0; j < KW; ++j)
                    o[t][i] = fmaf(s[t][j], w[t + 3*j], o[t][i]);
        }

        // ---------------- Store: one float4 per token ----------------------
#pragma unroll
        for (int t = 0; t < TPT; ++t) {
            float* op = out + ((size_t)(b * NPOS + n0 + t)) * DCH + hh * HD + cs * CPT;
            *(float4*)op = make_float4(o[t][0], o[t][1], o[t][2], o[t][3]);
        }

        // ---------------- Drain prefetch into the other buffer -------------
        if (it + 1 < NT4) {
            write_lds(cur ^ 1, kn, vn);
#pragma unroll
            for (int i = 0; i < CPT; ++i) qv[i] = qn[i];
        }
        __syncthreads();
    }
}

extern "C" void kernel_launch(void* const* d_in, const int* in_sizes, int n_in,
                              void* d_out, int out_size, void* d_ws, size_t ws_size,
                              hipStream_t stream) {
    const float* q = (const float*)d_in[0];
    const float* k = (const float*)d_in[1];
    const float* v = (const float*)d_in[2];
    float* out = (float*)d_out;

    const int grid = 4 * NH * NTILES / NT4;   // 2048 tiles / 4 = 512 blocks
    hipLaunchKernelGGL(dilate_attn_kernel, dim3(grid), dim3(256), 0, stream,
                       q, k, v, out);
}

// Round 7
// 148.173 us; speedup vs baseline: 1.5780x; 1.0426x over previous
//
#include <hip/hip_runtime.h>
#include <math.h>

#define NPOS 4096
#define DCH  512
#define HD   32
#define NH   16
#define KW   9
#define DIL  3
#define PAD  12
#define TILE   256
#define NTILES (NPOS / TILE)        // 16
#define SPANT  (TILE + 2*PAD)       // 280 tokens staged per tile
#define ROWF4  (SPANT / 4)          // 70 float4 per channel row
#define PITCH  280                  // bf16 elems per LDS row (560 B = 140 words)
#define NUNIT  (HD * ROWF4 * 2)     // 4480 staging float4 units (k then v)
#define CSPL   8                    // channel-split lanes
#define CPT    (HD / CSPL)          // 4 channels per thread
#define TPT    4                    // tokens per thread
#define WSPAN  28                   // 4 tokens x 9 taps span 28 tokens
#define BLK    512

typedef unsigned short ushort_t;

__device__ __forceinline__ ushort_t f2bf(float f) {
    unsigned u = __float_as_uint(f);
    unsigned r = (u + 0x7FFFu + ((u >> 16) & 1u)) >> 16;   // RNE
    return (ushort_t)r;
}
__device__ __forceinline__ float bf2f(ushort_t h) {
    return __uint_as_float(((unsigned)h) << 16);
}

__global__ __launch_bounds__(BLK) void dilate_attn_kernel(
    const float* __restrict__ q,
    const float* __restrict__ k,
    const float* __restrict__ v,
    float* __restrict__ out)
{
    __shared__ __align__(16) ushort_t ks[HD * PITCH];   // 17920 B
    __shared__ __align__(16) ushort_t vs[HD * PITCH];   // 17920 B

    const int bh   = blockIdx.x >> 4;            // 0..63 (b*16+h)
    const int tile = blockIdx.x & (NTILES - 1);  // 0..15
    const int n0t  = tile * TILE;
    const int ws   = n0t - PAD;                  // staged span start
    const bool easy = (tile > 0) && (tile < NTILES - 1);

    const size_t cb = (size_t)bh * HD * NPOS;
    const float* kg = k + cb;
    const float* vg = v + cb;
    const float* qg = q + cb;

    // ---------------- Stage k,v as bf16 into LDS (coalesced float4 loads) --
    for (int p = threadIdx.x; p < NUNIT; p += BLK) {
        const bool isv = (p >= NUNIT / 2);
        int rem = isv ? (p - NUNIT / 2) : p;
        int row = rem / ROWF4;                   // channel 0..31
        int c4  = rem - row * ROWF4;             // float4 col 0..69
        int g0  = ws + c4 * 4;
        const float* src = (isv ? vg : kg) + (size_t)row * NPOS;
        float4 x;
        if (easy || (g0 >= 0 && g0 + 4 <= NPOS)) {
            x = *(const float4*)(src + g0);
        } else {                                  // tiles 0 / 15 only
            int i0 = min(max(g0 + 0, 0), NPOS - 1);
            int i1 = min(max(g0 + 1, 0), NPOS - 1);
            int i2 = min(max(g0 + 2, 0), NPOS - 1);
            int i3 = min(max(g0 + 3, 0), NPOS - 1);
            x = make_float4(src[i0], src[i1], src[i2], src[i3]);
        }
        ushort4 bx;
        bx.x = f2bf(x.x); bx.y = f2bf(x.y); bx.z = f2bf(x.z); bx.w = f2bf(x.w);
        ushort_t* dst = isv ? vs : ks;
        *(ushort4*)&dst[row * PITCH + c4 * 4] = bx;   // 8B-aligned b64 write
    }

    // ---------------- q loads (fp32 float4, overlap staging latency) -------
    const int cs = threadIdx.x & (CSPL - 1);     // channel quad slot
    const int lg = threadIdx.x >> 3;             // 0..63: token group in tile
    const int n0 = n0t + lg * TPT;               // first token this thread owns

    float4 qv[CPT];
#pragma unroll
    for (int i = 0; i < CPT; ++i)
        qv[i] = *(const float4*)(qg + (size_t)(cs * CPT + i) * NPOS + n0);

    __syncthreads();

    // ---------------- Pass 1: partial scores from LDS k (bf16) -------------
    float s[TPT][KW];
#pragma unroll
    for (int t = 0; t < TPT; ++t)
#pragma unroll
        for (int j = 0; j < KW; ++j) s[t][j] = 0.0f;

#pragma unroll
    for (int i = 0; i < CPT; ++i) {
        int row = cs * CPT + i;
        const ushort4* wp = (const ushort4*)&ks[row * PITCH + lg * TPT];
        float w[WSPAN];
#pragma unroll
        for (int u = 0; u < WSPAN / 4; ++u) {
            ushort4 x = wp[u];
            w[4*u]   = bf2f(x.x); w[4*u+1] = bf2f(x.y);
            w[4*u+2] = bf2f(x.z); w[4*u+3] = bf2f(x.w);
        }
        float qt[TPT] = {qv[i].x, qv[i].y, qv[i].z, qv[i].w};
#pragma unroll
        for (int t = 0; t < TPT; ++t)
#pragma unroll
            for (int j = 0; j < KW; ++j)
                s[t][j] = fmaf(qt[t], w[t + 3*j], s[t][j]);
    }

    // Reduce partial scores across the 8 channel-split lanes
#pragma unroll
    for (int t = 0; t < TPT; ++t)
#pragma unroll
        for (int j = 0; j < KW; ++j) {
            float x = s[t][j];
            x += __shfl_xor(x, 1);
            x += __shfl_xor(x, 2);
            x += __shfl_xor(x, 4);
            s[t][j] = x;
        }

    // ---------------- Softmax per token --------------------------------------
    const float scale = 0.17677669529663687f;    // 32^-0.5
    if (easy) {                                  // interior: all taps valid
#pragma unroll
        for (int t = 0; t < TPT; ++t) {
            float m = -INFINITY;
#pragma unroll
            for (int j = 0; j < KW; ++j) {
                float x = s[t][j] * scale;
                s[t][j] = x;
                m = fmaxf(m, x);
            }
            float sum = 0.0f;
#pragma unroll
            for (int j = 0; j < KW; ++j) {
                float e = __expf(s[t][j] - m);
                s[t][j] = e;
                sum += e;
            }
            float inv = 1.0f / sum;
#pragma unroll
            for (int j = 0; j < KW; ++j) s[t][j] *= inv;
        }
    } else {                                     // edge tiles: mask invalid taps
#pragma unroll
        for (int t = 0; t < TPT; ++t) {
            float m = -INFINITY;
#pragma unroll
            for (int j = 0; j < KW; ++j) {
                float valid = ((unsigned)(n0 + t + 3*j - PAD) < NPOS) ? 1.0f : 0.0f;
                float x = s[t][j] * scale * valid;   // invalid logit = exactly 0
                s[t][j] = x;
                m = fmaxf(m, x);
            }
            float sum = 0.0f;
#pragma unroll
            for (int j = 0; j < KW; ++j) {
                float e = __expf(s[t][j] - m);
                s[t][j] = e;
                sum += e;
            }
            float inv = 1.0f / sum;
#pragma unroll
            for (int j = 0; j < KW; ++j) {
                float valid = ((unsigned)(n0 + t + 3*j - PAD) < NPOS) ? 1.0f : 0.0f;
                s[t][j] *= inv * valid;          // invalid taps contribute nothing
            }
        }
    }

    // ---------------- Pass 2: output from LDS v (bf16) ---------------------
    float o[TPT][CPT];
#pragma unroll
    for (int t = 0; t < TPT; ++t)
#pragma unroll
        for (int i = 0; i < CPT; ++i) o[t][i] = 0.0f;

#pragma unroll
    for (int i = 0; i < CPT; ++i) {
        int row = cs * CPT + i;
        const ushort4* wp = (const ushort4*)&vs[row * PITCH + lg * TPT];
        float w[WSPAN];
#pragma unroll
        for (int u = 0; u < WSPAN / 4; ++u) {
            ushort4 x = wp[u];
            w[4*u]   = bf2f(x.x); w[4*u+1] = bf2f(x.y);
            w[4*u+2] = bf2f(x.z); w[4*u+3] = bf2f(x.w);
        }
#pragma unroll
        for (int t = 0; t < TPT; ++t)
#pragma unroll
            for (int j = 0; j < KW; ++j)
                o[t][i] = fmaf(s[t][j], w[t + 3*j], o[t][i]);
    }

    // ---------------- Store: one float4 per token --------------------------
    const int b  = bh >> 4;
    const int hh = bh & (NH - 1);
#pragma unroll
    for (int t = 0; t < TPT; ++t) {
        float* op = out + ((size_t)(b * NPOS + n0 + t)) * DCH + hh * HD + cs * CPT;
        *(float4*)op = make_float4(o[t][0], o[t][1], o[t][2], o[t][3]);
    }
}

extern "C" void kernel_launch(void* const* d_in, const int* in_sizes, int n_in,
                              void* d_out, int out_size, void* d_ws, size_t ws_size,
                              hipStream_t stream) {
    const float* q = (const float*)d_in[0];
    const float* k = (const float*)d_in[1];
    const float* v = (const float*)d_in[2];
    float* out = (float*)d_out;

    const int grid = 4 * NH * NTILES;   // 64 bh * 16 tiles = 1024 blocks
    hipLaunchKernelGGL(dilate_attn_kernel, dim3(grid), dim3(BLK), 0, stream,
                       q, k, v, out);
}